// Round 2
// baseline (89043.268 us; speedup 1.0000x reference)
//
#include <hip/hip_runtime.h>

#define TPB 256

// ================= edge list construction =================
__global__ void build_edges_k(const int* __restrict__ ea, const int* __restrict__ eb,
                              const int* __restrict__ pb,
                              int Ea, int Eb, int NC, int Na,
                              int* __restrict__ src, int* __restrict__ dst) {
    int e = blockIdx.x * TPB + threadIdx.x;
    int E = Ea + Eb + 2 * NC;
    if (e >= E) return;
    int s, d;
    if (e < Ea) { s = ea[2*e]; d = ea[2*e+1]; }
    else if (e < Ea + Eb) { int i = e - Ea; s = eb[2*i] + Na; d = eb[2*i+1] + Na; }
    else if (e < Ea + Eb + NC) { int c = e - Ea - Eb; s = pb[c]; d = pb[NC + c] + Na; }
    else { int c = e - Ea - Eb - NC; s = pb[NC + c] + Na; d = pb[c]; }
    src[e] = s; dst[e] = d;
}

__global__ void count_k(const int* __restrict__ dst, int* __restrict__ counts, int E) {
    int e = blockIdx.x * TPB + threadIdx.x;
    if (e < E) atomicAdd(&counts[dst[e]], 1);
}

// ---- exclusive scan over counts[0..N-1] -> offs (1024 elems / block) ----
__global__ void scan1_k(const int* __restrict__ counts, int* __restrict__ offs,
                        int* __restrict__ partials, int N) {
    __shared__ int sdata[TPB];
    int tid = threadIdx.x;
    int base = blockIdx.x * 1024;
    int v[4]; int s = 0;
    #pragma unroll
    for (int r = 0; r < 4; r++) {
        int idx = base + tid * 4 + r;
        v[r] = (idx < N) ? counts[idx] : 0;
        s += v[r];
    }
    sdata[tid] = s;
    __syncthreads();
    for (int o = 1; o < TPB; o <<= 1) {
        int t = (tid >= o) ? sdata[tid - o] : 0;
        __syncthreads();
        sdata[tid] += t;
        __syncthreads();
    }
    if (tid == TPB - 1) partials[blockIdx.x] = sdata[TPB - 1];
    int run = sdata[tid] - s;  // exclusive prefix of this thread's chunk
    #pragma unroll
    for (int r = 0; r < 4; r++) {
        int idx = base + tid * 4 + r;
        if (idx < N) offs[idx] = run;
        run += v[r];
    }
}

__global__ void scan2_k(int* __restrict__ partials, int nPart) {
    if (blockIdx.x == 0 && threadIdx.x == 0) {
        int acc = 0;
        for (int i = 0; i < nPart; i++) { int t = partials[i]; partials[i] = acc; acc += t; }
    }
}

__global__ void scan3_k(int* __restrict__ offs, const int* __restrict__ partials, int N, int E) {
    int i = blockIdx.x * TPB + threadIdx.x;
    if (i < N) offs[i] += partials[i >> 10];
    else if (i == N) offs[N] = E;
}

__global__ void fill_k(const int* __restrict__ src, const int* __restrict__ dst,
                       const int* __restrict__ offs, int* __restrict__ cursor,
                       int* __restrict__ eSrc, int* __restrict__ eOrig, int E) {
    int e = blockIdx.x * TPB + threadIdx.x;
    if (e >= E) return;
    int d = dst[e];
    int p = offs[d] + atomicAdd(&cursor[d], 1);
    eSrc[p] = src[e];
    eOrig[p] = e;
}

// ================= h0 in CSR order =================
__global__ void h0c_k(const float* __restrict__ xa, const float* __restrict__ xb,
                      const float* __restrict__ efa, const float* __restrict__ efb,
                      const int* __restrict__ eSrc, const int* __restrict__ eOrig,
                      int Ea, int Eb, int Na, int E,
                      const float* __restrict__ W_in, const float* __restrict__ b_in,
                      float* __restrict__ h0c) {
    __shared__ float Wl[6 * 64];
    __shared__ float bl[64];
    for (int t = threadIdx.x; t < 6 * 64; t += TPB) Wl[t] = W_in[t];
    if (threadIdx.x < 64) bl[threadIdx.x] = b_in[threadIdx.x];
    __syncthreads();
    int gid = blockIdx.x * TPB + threadIdx.x;
    if (gid >= E * 64) return;
    int k = gid >> 6, j = gid & 63;
    int e = eOrig[k];
    int s = eSrc[k];
    const float* xp = (s < Na) ? (xa + (size_t)s * 5) : (xb + (size_t)(s - Na) * 5);
    float efv = (e < Ea) ? efa[e] : ((e < Ea + Eb) ? efb[e - Ea] : 999.0f);
    float acc = bl[j];
    #pragma unroll
    for (int i = 0; i < 5; i++) acc += xp[i] * Wl[i * 64 + j];
    acc += efv * Wl[5 * 64 + j];
    h0c[(size_t)gid] = fmaxf(acc, 0.0f);
}

// ================= fused step kernel =================
// MODE 0: init   agg = segsum(h0);            out = agg @ W_msg + b    (64 cols)
// MODE 1: mid    h = relu(h0+prev[src]); agg = segsum(h); out = agg@W_msg+b
// MODE 2: final  h = relu(h0+prev[src]); hsave; agg = segsum(h);
//                out = node_h = relu([x, agg] @ W_node + b)            (32 cols)
template<int MODE>
__global__ __launch_bounds__(TPB) void step_k(const float* __restrict__ h0c,
                                              const int* __restrict__ eSrc,
                                              const int* __restrict__ eOrig,
                                              const int* __restrict__ offs,
                                              const float* __restrict__ prevW,
                                              float* __restrict__ outW,
                                              const float* __restrict__ W,
                                              const float* __restrict__ b,
                                              int N, int off,
                                              float* __restrict__ hsave,
                                              const float* __restrict__ xa,
                                              const float* __restrict__ xb, int Na) {
    __shared__ __align__(16) float Wl[64 * 64];
    __shared__ float bl[64];
    __shared__ __align__(16) float aggS[64 * 64];
    int tid = threadIdx.x;
    int nW = (MODE == 2) ? 69 * 32 : 64 * 64;
    for (int t = tid; t < nW; t += TPB) Wl[t] = W[t];
    int nB = (MODE == 2) ? 32 : 64;
    if (tid < nB) bl[tid] = b[tid];

    int base = blockIdx.x * 64;
    int slot = tid >> 4;      // 0..15
    int l = tid & 15;         // float4 lane within row (cols 4l..4l+3)
    const float4* h04 = (const float4*)h0c;
    const float4* pw4 = (const float4*)prevW;
    float4* hs4 = (float4*)hsave;
    float4* ag4w = (float4*)aggS;

    #pragma unroll
    for (int g = 0; g < 4; g++) {
        int d = base + g * 16 + slot;
        float ax = 0.f, ay = 0.f, az = 0.f, aw = 0.f;
        if (d < N) {
            int beg = offs[d], end = offs[d + 1];
            for (int k = beg; k < end; k++) {
                float4 v = h04[(size_t)k * 16 + l];
                if (MODE >= 1) {
                    int s = eSrc[k];
                    float4 p = pw4[(size_t)s * 16 + l];
                    v.x = fmaxf(v.x + p.x, 0.f);
                    v.y = fmaxf(v.y + p.y, 0.f);
                    v.z = fmaxf(v.z + p.z, 0.f);
                    v.w = fmaxf(v.w + p.w, 0.f);
                }
                if (MODE == 2) {
                    int eo = eOrig[k];
                    if (eo >= off) hs4[(size_t)(eo - off) * 16 + l] = v;
                }
                ax += v.x; ay += v.y; az += v.z; aw += v.w;
            }
        }
        float4 o; o.x = ax; o.y = ay; o.z = az; o.w = aw;
        ag4w[(g * 16 + slot) * 16 + l] = o;
    }
    __syncthreads();

    const float4* ag4 = (const float4*)aggS;
    if (MODE != 2) {
        // ---- GEMM: out[n][c] = bl[c] + sum_i aggS[n][i]*Wl[i][c], 64 nodes x 64 cols
        int c = tid & 63;
        int n0 = (tid >> 6) * 16;
        float acc[16];
        #pragma unroll
        for (int r = 0; r < 16; r++) acc[r] = bl[c];
        #pragma unroll
        for (int i4 = 0; i4 < 16; i4++) {
            float w0 = Wl[(4 * i4 + 0) * 64 + c];
            float w1 = Wl[(4 * i4 + 1) * 64 + c];
            float w2 = Wl[(4 * i4 + 2) * 64 + c];
            float w3 = Wl[(4 * i4 + 3) * 64 + c];
            #pragma unroll
            for (int r = 0; r < 16; r++) {
                float4 a = ag4[(n0 + r) * 16 + i4];
                acc[r] += a.x * w0 + a.y * w1 + a.z * w2 + a.w * w3;
            }
        }
        #pragma unroll
        for (int r = 0; r < 16; r++) {
            int d = base + n0 + r;
            if (d < N) outW[(size_t)d * 64 + c] = acc[r];
        }
    } else {
        // ---- node_h[n][c] = relu(bl[c] + sum_{i<5} x[i]*Wn[i][c] + sum_{i<64} agg[i]*Wn[5+i][c])
        int c = tid & 31;
        int n0 = (tid >> 5) * 8;
        float acc[8];
        #pragma unroll
        for (int r = 0; r < 8; r++) acc[r] = bl[c];
        for (int r = 0; r < 8; r++) {
            int d = base + n0 + r;
            if (d < N) {
                const float* xp = (d < Na) ? (xa + (size_t)d * 5) : (xb + (size_t)(d - Na) * 5);
                #pragma unroll
                for (int i = 0; i < 5; i++) acc[r] += xp[i] * Wl[i * 32 + c];
            }
        }
        #pragma unroll
        for (int i4 = 0; i4 < 16; i4++) {
            float w0 = Wl[(5 + 4 * i4 + 0) * 32 + c];
            float w1 = Wl[(5 + 4 * i4 + 1) * 32 + c];
            float w2 = Wl[(5 + 4 * i4 + 2) * 32 + c];
            float w3 = Wl[(5 + 4 * i4 + 3) * 32 + c];
            #pragma unroll
            for (int r = 0; r < 8; r++) {
                float4 a = ag4[(n0 + r) * 16 + i4];
                acc[r] += a.x * w0 + a.y * w1 + a.z * w2 + a.w * w3;
            }
        }
        #pragma unroll
        for (int r = 0; r < 8; r++) {
            int d = base + n0 + r;
            if (d < N) outW[(size_t)d * 32 + c] = fmaxf(acc[r], 0.f);
        }
    }
}

// ================= MLP head =================
#define TM2 32
#define MSTR 260  // floats per row; 1040 B (16B aligned)

__device__ __forceinline__ void mlp_layer2(const float* __restrict__ W, const float* __restrict__ b,
                                           int in, int out, int lgout,
                                           const float* __restrict__ A, float* __restrict__ B) {
    int pairs = out * (TM2 / 8);
    const float4* a4b = (const float4*)A;
    for (int p = threadIdx.x; p < pairs; p += TPB) {
        int j = p & (out - 1);
        int r0 = (p >> lgout) * 8;
        float acc[8];
        float bj = b[j];
        #pragma unroll
        for (int r = 0; r < 8; r++) acc[r] = bj;
        for (int i4 = 0; i4 < (in >> 2); i4++) {
            int i = i4 * 4;
            float w0 = W[(i + 0) * out + j];
            float w1 = W[(i + 1) * out + j];
            float w2 = W[(i + 2) * out + j];
            float w3 = W[(i + 3) * out + j];
            #pragma unroll
            for (int r = 0; r < 8; r++) {
                float4 a = a4b[(r0 + r) * 65 + i4];
                acc[r] += a.x * w0 + a.y * w1 + a.z * w2 + a.w * w3;
            }
        }
        #pragma unroll
        for (int r = 0; r < 8; r++) B[(r0 + r) * MSTR + j] = fmaxf(acc[r], 0.0f);
    }
    __syncthreads();
}

__global__ __launch_bounds__(TPB) void mlp2_k(const float* __restrict__ node_h,
                                              const float* __restrict__ hsave,
                                              const int* __restrict__ pb, int NC, int Na,
                                              const float* __restrict__ W1, const float* __restrict__ b1,
                                              const float* __restrict__ W2, const float* __restrict__ b2,
                                              const float* __restrict__ W3, const float* __restrict__ b3,
                                              const float* __restrict__ W4, const float* __restrict__ b4,
                                              const float* __restrict__ W5, const float* __restrict__ b5,
                                              const float* __restrict__ W6, const float* __restrict__ b6,
                                              float* __restrict__ out) {
    __shared__ __align__(16) float A[TM2 * MSTR];
    __shared__ __align__(16) float B[TM2 * MSTR];
    int c0 = blockIdx.x * TM2;
    for (int idx = threadIdx.x; idx < TM2 * 128; idx += TPB) {
        int r = idx >> 7, col = idx & 127;
        int c = c0 + r;
        float v = 0.0f;
        if (c < NC) {
            if (col < 32) v = node_h[(size_t)pb[c] * 32 + col];
            else if (col < 64) v = node_h[(size_t)(Na + pb[NC + c]) * 32 + (col - 32)];
            else v = hsave[(size_t)c * 64 + (col - 64)] + hsave[(size_t)(NC + c) * 64 + (col - 64)];
        }
        A[r * MSTR + col] = v;
    }
    __syncthreads();
    mlp_layer2(W1, b1, 128, 128, 7, A, B);
    mlp_layer2(W2, b2, 128, 256, 8, B, A);
    mlp_layer2(W3, b3, 256, 256, 8, A, B);
    mlp_layer2(W4, b4, 256, 128, 7, B, A);
    mlp_layer2(W5, b5, 128, 64, 6, A, B);
    if (threadIdx.x < TM2) {
        int r = threadIdx.x, c = c0 + r;
        if (c < NC) {
            float z[4];
            #pragma unroll
            for (int k = 0; k < 4; k++) {
                float acc = b6[k];
                for (int i = 0; i < 64; i++) acc += B[r * MSTR + i] * W6[i * 4 + k];
                z[k] = acc;
            }
            float m = fmaxf(fmaxf(z[0], z[1]), fmaxf(z[2], z[3]));
            float e0 = expf(z[0] - m), e1 = expf(z[1] - m), e2 = expf(z[2] - m), e3 = expf(z[3] - m);
            float inv = 1.0f / (e0 + e1 + e2 + e3);
            int am = 0; float bm = z[0];
            if (z[1] > bm) { bm = z[1]; am = 1; }
            if (z[2] > bm) { bm = z[2]; am = 2; }
            if (z[3] > bm) { bm = z[3]; am = 3; }
            out[(size_t)c * 3 + 0] = (float)pb[c];
            out[(size_t)c * 3 + 1] = (float)pb[NC + c];
            out[(size_t)c * 3 + 2] = (float)am;
            float* po = out + (size_t)NC * 3 + (size_t)c * 4;
            po[0] = e0 * inv; po[1] = e1 * inv; po[2] = e2 * inv; po[3] = e3 * inv;
        }
    }
}

extern "C" void kernel_launch(void* const* d_in, const int* in_sizes, int n_in,
                              void* d_out, int out_size, void* d_ws, size_t ws_size,
                              hipStream_t stream) {
    const float* xa   = (const float*)d_in[0];
    const float* efa  = (const float*)d_in[1];
    const int*   ea   = (const int*)d_in[2];
    const float* xb   = (const float*)d_in[3];
    const float* efb  = (const float*)d_in[4];
    const int*   eb   = (const int*)d_in[5];
    const int*   pb   = (const int*)d_in[6];
    const float* W_in   = (const float*)d_in[7];
    const float* b_in   = (const float*)d_in[8];
    const float* W_msg  = (const float*)d_in[9];
    const float* b_msg  = (const float*)d_in[10];
    const float* W_node = (const float*)d_in[11];
    const float* b_node = (const float*)d_in[12];
    const float* W1 = (const float*)d_in[13]; const float* b1 = (const float*)d_in[14];
    const float* W2 = (const float*)d_in[15]; const float* b2 = (const float*)d_in[16];
    const float* W3 = (const float*)d_in[17]; const float* b3 = (const float*)d_in[18];
    const float* W4 = (const float*)d_in[19]; const float* b4 = (const float*)d_in[20];
    const float* W5 = (const float*)d_in[21]; const float* b5 = (const float*)d_in[22];
    const float* W6 = (const float*)d_in[23]; const float* b6 = (const float*)d_in[24];

    int Na = in_sizes[0] / 5;
    int Ea = in_sizes[2] / 2;
    int Nb = in_sizes[3] / 5;
    int Eb = in_sizes[5] / 2;
    int NC = in_sizes[6] / 2;
    int N = Na + Nb;
    int E = Ea + Eb + 2 * NC;
    int off = Ea + Eb;
    int nPart = (N + 1023) / 1024;

    char* p = (char*)d_ws;
    auto alloc = [&](size_t bytes) { char* r = p; p += (bytes + 255) & ~(size_t)255; return r; };
    int*   src    = (int*)alloc((size_t)E * 4);
    int*   dst    = (int*)alloc((size_t)E * 4);
    int*   counts = (int*)alloc((size_t)N * 4);
    int*   offs   = (int*)alloc((size_t)(N + 1) * 4);
    int*   cursor = (int*)alloc((size_t)N * 4);
    int*   parts  = (int*)alloc((size_t)nPart * 4);
    int*   eSrc   = (int*)alloc((size_t)E * 4);
    int*   eOrig  = (int*)alloc((size_t)E * 4);
    float* h0c    = (float*)alloc((size_t)E * 64 * 4);
    float* aggWA  = (float*)alloc((size_t)N * 64 * 4);
    float* aggWB  = (float*)alloc((size_t)N * 64 * 4);
    float* hsave  = (float*)alloc((size_t)2 * NC * 64 * 4);
    float* nodeh  = (float*)alloc((size_t)N * 32 * 4);
    if ((size_t)(p - (char*)d_ws) > ws_size) return;  // insufficient workspace -> visible failure

    hipMemsetAsync(counts, 0, (size_t)N * 4, stream);
    hipMemsetAsync(cursor, 0, (size_t)N * 4, stream);

    build_edges_k<<<(E + TPB - 1) / TPB, TPB, 0, stream>>>(ea, eb, pb, Ea, Eb, NC, Na, src, dst);
    count_k<<<(E + TPB - 1) / TPB, TPB, 0, stream>>>(dst, counts, E);
    scan1_k<<<nPart, TPB, 0, stream>>>(counts, offs, parts, N);
    scan2_k<<<1, 64, 0, stream>>>(parts, nPart);
    scan3_k<<<(N + 1 + TPB - 1) / TPB, TPB, 0, stream>>>(offs, parts, N, E);
    fill_k<<<(E + TPB - 1) / TPB, TPB, 0, stream>>>(src, dst, offs, cursor, eSrc, eOrig, E);
    h0c_k<<<(E * 64 + TPB - 1) / TPB, TPB, 0, stream>>>(xa, xb, efa, efb, eSrc, eOrig,
                                                        Ea, Eb, Na, E, W_in, b_in, h0c);

    int nblk = (N + 63) / 64;
    step_k<0><<<nblk, TPB, 0, stream>>>(h0c, eSrc, eOrig, offs, nullptr, aggWA,
                                        W_msg, b_msg, N, off, nullptr, xa, xb, Na);
    float* cur = aggWA; float* nxt = aggWB;
    for (int t = 1; t <= 99; t++) {
        step_k<1><<<nblk, TPB, 0, stream>>>(h0c, eSrc, eOrig, offs, cur, nxt,
                                            W_msg, b_msg, N, off, nullptr, xa, xb, Na);
        float* tmp = cur; cur = nxt; nxt = tmp;
    }
    step_k<2><<<nblk, TPB, 0, stream>>>(h0c, eSrc, eOrig, offs, cur, nodeh,
                                        W_node, b_node, N, off, hsave, xa, xb, Na);

    mlp2_k<<<(NC + TM2 - 1) / TM2, TPB, 0, stream>>>(nodeh, hsave, pb, NC, Na,
                                                     W1, b1, W2, b2, W3, b3, W4, b4, W5, b5, W6, b6,
                                                     (float*)d_out);
}

// Round 3
// 75035.803 us; speedup vs baseline: 1.1867x; 1.1867x over previous
//
#include <hip/hip_runtime.h>

#define TPB 256

// ================= edge list construction =================
__global__ void build_edges_k(const int* __restrict__ ea, const int* __restrict__ eb,
                              const int* __restrict__ pb,
                              int Ea, int Eb, int NC, int Na,
                              int* __restrict__ src, int* __restrict__ dst) {
    int e = blockIdx.x * TPB + threadIdx.x;
    int E = Ea + Eb + 2 * NC;
    if (e >= E) return;
    int s, d;
    if (e < Ea) { s = ea[2*e]; d = ea[2*e+1]; }
    else if (e < Ea + Eb) { int i = e - Ea; s = eb[2*i] + Na; d = eb[2*i+1] + Na; }
    else if (e < Ea + Eb + NC) { int c = e - Ea - Eb; s = pb[c]; d = pb[NC + c] + Na; }
    else { int c = e - Ea - Eb - NC; s = pb[NC + c] + Na; d = pb[c]; }
    src[e] = s; dst[e] = d;
}

__global__ void count_k(const int* __restrict__ dst, int* __restrict__ counts, int E) {
    int e = blockIdx.x * TPB + threadIdx.x;
    if (e < E) atomicAdd(&counts[dst[e]], 1);
}

// ---- exclusive scan over counts[0..N-1] -> offs (1024 elems / block) ----
__global__ void scan1_k(const int* __restrict__ counts, int* __restrict__ offs,
                        int* __restrict__ partials, int N) {
    __shared__ int sdata[TPB];
    int tid = threadIdx.x;
    int base = blockIdx.x * 1024;
    int v[4]; int s = 0;
    #pragma unroll
    for (int r = 0; r < 4; r++) {
        int idx = base + tid * 4 + r;
        v[r] = (idx < N) ? counts[idx] : 0;
        s += v[r];
    }
    sdata[tid] = s;
    __syncthreads();
    for (int o = 1; o < TPB; o <<= 1) {
        int t = (tid >= o) ? sdata[tid - o] : 0;
        __syncthreads();
        sdata[tid] += t;
        __syncthreads();
    }
    if (tid == TPB - 1) partials[blockIdx.x] = sdata[TPB - 1];
    int run = sdata[tid] - s;
    #pragma unroll
    for (int r = 0; r < 4; r++) {
        int idx = base + tid * 4 + r;
        if (idx < N) offs[idx] = run;
        run += v[r];
    }
}

__global__ void scan2_k(int* __restrict__ partials, int nPart) {
    if (blockIdx.x == 0 && threadIdx.x == 0) {
        int acc = 0;
        for (int i = 0; i < nPart; i++) { int t = partials[i]; partials[i] = acc; acc += t; }
    }
}

__global__ void scan3_k(int* __restrict__ offs, const int* __restrict__ partials, int N, int E) {
    int i = blockIdx.x * TPB + threadIdx.x;
    if (i < N) offs[i] += partials[i >> 10];
    else if (i == N) offs[N] = E;
}

__global__ void fill_k(const int* __restrict__ src, const int* __restrict__ dst,
                       const int* __restrict__ offs, int* __restrict__ cursor,
                       int* __restrict__ eSrc, int* __restrict__ eOrig, int E) {
    int e = blockIdx.x * TPB + threadIdx.x;
    if (e >= E) return;
    int d = dst[e];
    int p = offs[d] + atomicAdd(&cursor[d], 1);
    eSrc[p] = src[e];
    eOrig[p] = e;
}

// ================= h0 in CSR order (f32) =================
__global__ void h0c_k(const float* __restrict__ xa, const float* __restrict__ xb,
                      const float* __restrict__ efa, const float* __restrict__ efb,
                      const int* __restrict__ eSrc, const int* __restrict__ eOrig,
                      int Ea, int Eb, int Na, int E,
                      const float* __restrict__ W_in, const float* __restrict__ b_in,
                      float* __restrict__ h0c) {
    __shared__ float Wl[6 * 64];
    __shared__ float bl[64];
    for (int t = threadIdx.x; t < 6 * 64; t += TPB) Wl[t] = W_in[t];
    if (threadIdx.x < 64) bl[threadIdx.x] = b_in[threadIdx.x];
    __syncthreads();
    int gid = blockIdx.x * TPB + threadIdx.x;
    if (gid >= E * 64) return;
    int k = gid >> 6, j = gid & 63;
    int e = eOrig[k];
    int s = eSrc[k];
    const float* xp = (s < Na) ? (xa + (size_t)s * 5) : (xb + (size_t)(s - Na) * 5);
    float efv = (e < Ea) ? efa[e] : ((e < Ea + Eb) ? efb[e - Ea] : 999.0f);
    float acc = bl[j];
    #pragma unroll
    for (int i = 0; i < 5; i++) acc += xp[i] * Wl[i * 64 + j];
    acc += efv * Wl[5 * 64 + j];
    h0c[(size_t)gid] = fmaxf(acc, 0.0f);
}

// ================= slim CSR gather: agg[d] = sum over in-edges of relu(h0 + aggW[src]) =================
// MODE 0: agg = segsum(h0)                      (init, h_1 = h0)
// MODE 1: agg = segsum(relu(h0 + prevW[src]))
// MODE 2: MODE 1 + save h for candidate edges (eOrig >= off)
template<int MODE>
__global__ __launch_bounds__(TPB) void gather_k(const float4* __restrict__ h04,
                                                const int* __restrict__ eSrc,
                                                const int* __restrict__ eOrig,
                                                const int* __restrict__ offs,
                                                const float4* __restrict__ prevW,
                                                float4* __restrict__ agg,
                                                float4* __restrict__ hsave,
                                                int N, int off) {
    int gid = blockIdx.x * TPB + threadIdx.x;
    if (gid >= N * 16) return;
    int d = gid >> 4, l = gid & 15;
    int beg = offs[d], end = offs[d + 1];
    float ax = 0.f, ay = 0.f, az = 0.f, aw = 0.f;
    for (int k = beg; k < end; k++) {
        float4 v = h04[(size_t)k * 16 + l];
        if (MODE >= 1) {
            int s = eSrc[k];
            float4 p = prevW[(size_t)s * 16 + l];
            v.x = fmaxf(v.x + p.x, 0.f);
            v.y = fmaxf(v.y + p.y, 0.f);
            v.z = fmaxf(v.z + p.z, 0.f);
            v.w = fmaxf(v.w + p.w, 0.f);
        }
        if (MODE == 2) {
            int eo = eOrig[k];
            if (eo >= off) hsave[(size_t)(eo - off) * 16 + l] = v;
        }
        ax += v.x; ay += v.y; az += v.z; aw += v.w;
    }
    float4 o; o.x = ax; o.y = ay; o.z = az; o.w = aw;
    agg[(size_t)d * 16 + l] = o;
}

// ================= per-node GEMM: aggW = agg @ W_msg + b_msg (64 nodes / block) =================
__global__ __launch_bounds__(TPB) void gemm_k(const float* __restrict__ agg,
                                              const float* __restrict__ W_msg,
                                              const float* __restrict__ b_msg,
                                              float* __restrict__ aggW, int N) {
    __shared__ __align__(16) float Wl[64 * 64];
    __shared__ float bl[64];
    __shared__ __align__(16) float actL[64 * 64];
    int tid = threadIdx.x;
    for (int t = tid; t < 4096; t += TPB) Wl[t] = W_msg[t];
    if (tid < 64) bl[tid] = b_msg[tid];
    size_t base = (size_t)blockIdx.x * 4096;
    size_t lim = (size_t)N * 64;
    for (int t = tid; t < 4096; t += TPB) {
        size_t g = base + t;
        actL[t] = (g < lim) ? agg[g] : 0.0f;
    }
    __syncthreads();
    int j = tid & 63;
    int n0 = (tid >> 6) * 16;
    float acc[16];
    #pragma unroll
    for (int k = 0; k < 16; k++) acc[k] = bl[j];
    const float4* act4 = (const float4*)actL;
    #pragma unroll
    for (int i4 = 0; i4 < 16; i4++) {
        float w0 = Wl[(4 * i4 + 0) * 64 + j];
        float w1 = Wl[(4 * i4 + 1) * 64 + j];
        float w2 = Wl[(4 * i4 + 2) * 64 + j];
        float w3 = Wl[(4 * i4 + 3) * 64 + j];
        #pragma unroll
        for (int k = 0; k < 16; k++) {
            float4 a = act4[(n0 + k) * 16 + i4];
            acc[k] += a.x * w0 + a.y * w1 + a.z * w2 + a.w * w3;
        }
    }
    #pragma unroll
    for (int k = 0; k < 16; k++) {
        size_t g2 = base + (size_t)(n0 + k) * 64 + j;
        if (g2 < lim) aggW[g2] = acc[k];
    }
}

// ================= node_h = relu([x, agg] @ W_node + b_node) =================
__global__ void nodeh_k(const float* __restrict__ xa, const float* __restrict__ xb,
                        int Na, int N,
                        const float* __restrict__ agg,
                        const float* __restrict__ W_node, const float* __restrict__ b_node,
                        float* __restrict__ node_h) {
    __shared__ float Wl[69 * 32];
    __shared__ float bl[32];
    for (int t = threadIdx.x; t < 69 * 32; t += TPB) Wl[t] = W_node[t];
    if (threadIdx.x < 32) bl[threadIdx.x] = b_node[threadIdx.x];
    __syncthreads();
    int gid = blockIdx.x * TPB + threadIdx.x;
    if (gid >= N * 32) return;
    int n = gid >> 5, j = gid & 31;
    const float* xp = (n < Na) ? (xa + (size_t)n * 5) : (xb + (size_t)(n - Na) * 5);
    float acc = bl[j];
    #pragma unroll
    for (int i = 0; i < 5; i++) acc += xp[i] * Wl[i * 32 + j];
    const float4* a4 = (const float4*)(agg + (size_t)n * 64);
    #pragma unroll
    for (int i4 = 0; i4 < 16; i4++) {
        float4 a = a4[i4];
        acc += a.x * Wl[(5 + 4 * i4 + 0) * 32 + j];
        acc += a.y * Wl[(5 + 4 * i4 + 1) * 32 + j];
        acc += a.z * Wl[(5 + 4 * i4 + 2) * 32 + j];
        acc += a.w * Wl[(5 + 4 * i4 + 3) * 32 + j];
    }
    node_h[gid] = fmaxf(acc, 0.0f);
}

// ================= MLP head =================
#define TM2 32
#define MSTR 260  // floats per row; 1040 B (16B aligned)

__device__ __forceinline__ void mlp_layer2(const float* __restrict__ W, const float* __restrict__ b,
                                           int in, int out, int lgout,
                                           const float* __restrict__ A, float* __restrict__ B) {
    int pairs = out * (TM2 / 8);
    const float4* a4b = (const float4*)A;
    for (int p = threadIdx.x; p < pairs; p += TPB) {
        int j = p & (out - 1);
        int r0 = (p >> lgout) * 8;
        float acc[8];
        float bj = b[j];
        #pragma unroll
        for (int r = 0; r < 8; r++) acc[r] = bj;
        for (int i4 = 0; i4 < (in >> 2); i4++) {
            int i = i4 * 4;
            float w0 = W[(i + 0) * out + j];
            float w1 = W[(i + 1) * out + j];
            float w2 = W[(i + 2) * out + j];
            float w3 = W[(i + 3) * out + j];
            #pragma unroll
            for (int r = 0; r < 8; r++) {
                float4 a = a4b[(r0 + r) * 65 + i4];
                acc[r] += a.x * w0 + a.y * w1 + a.z * w2 + a.w * w3;
            }
        }
        #pragma unroll
        for (int r = 0; r < 8; r++) B[(r0 + r) * MSTR + j] = fmaxf(acc[r], 0.0f);
    }
    __syncthreads();
}

__global__ __launch_bounds__(TPB) void mlp2_k(const float* __restrict__ node_h,
                                              const float* __restrict__ hsave,
                                              const int* __restrict__ pb, int NC, int Na,
                                              const float* __restrict__ W1, const float* __restrict__ b1,
                                              const float* __restrict__ W2, const float* __restrict__ b2,
                                              const float* __restrict__ W3, const float* __restrict__ b3,
                                              const float* __restrict__ W4, const float* __restrict__ b4,
                                              const float* __restrict__ W5, const float* __restrict__ b5,
                                              const float* __restrict__ W6, const float* __restrict__ b6,
                                              float* __restrict__ out) {
    __shared__ __align__(16) float A[TM2 * MSTR];
    __shared__ __align__(16) float B[TM2 * MSTR];
    int c0 = blockIdx.x * TM2;
    for (int idx = threadIdx.x; idx < TM2 * 128; idx += TPB) {
        int r = idx >> 7, col = idx & 127;
        int c = c0 + r;
        float v = 0.0f;
        if (c < NC) {
            if (col < 32) v = node_h[(size_t)pb[c] * 32 + col];
            else if (col < 64) v = node_h[(size_t)(Na + pb[NC + c]) * 32 + (col - 32)];
            else v = hsave[(size_t)c * 64 + (col - 64)] + hsave[(size_t)(NC + c) * 64 + (col - 64)];
        }
        A[r * MSTR + col] = v;
    }
    __syncthreads();
    mlp_layer2(W1, b1, 128, 128, 7, A, B);
    mlp_layer2(W2, b2, 128, 256, 8, B, A);
    mlp_layer2(W3, b3, 256, 256, 8, A, B);
    mlp_layer2(W4, b4, 256, 128, 7, B, A);
    mlp_layer2(W5, b5, 128, 64, 6, A, B);
    if (threadIdx.x < TM2) {
        int r = threadIdx.x, c = c0 + r;
        if (c < NC) {
            float z[4];
            #pragma unroll
            for (int k = 0; k < 4; k++) {
                float acc = b6[k];
                for (int i = 0; i < 64; i++) acc += B[r * MSTR + i] * W6[i * 4 + k];
                z[k] = acc;
            }
            float m = fmaxf(fmaxf(z[0], z[1]), fmaxf(z[2], z[3]));
            float e0 = expf(z[0] - m), e1 = expf(z[1] - m), e2 = expf(z[2] - m), e3 = expf(z[3] - m);
            float inv = 1.0f / (e0 + e1 + e2 + e3);
            int am = 0; float bm = z[0];
            if (z[1] > bm) { bm = z[1]; am = 1; }
            if (z[2] > bm) { bm = z[2]; am = 2; }
            if (z[3] > bm) { bm = z[3]; am = 3; }
            out[(size_t)c * 3 + 0] = (float)pb[c];
            out[(size_t)c * 3 + 1] = (float)pb[NC + c];
            out[(size_t)c * 3 + 2] = (float)am;
            float* po = out + (size_t)NC * 3 + (size_t)c * 4;
            po[0] = e0 * inv; po[1] = e1 * inv; po[2] = e2 * inv; po[3] = e3 * inv;
        }
    }
}

extern "C" void kernel_launch(void* const* d_in, const int* in_sizes, int n_in,
                              void* d_out, int out_size, void* d_ws, size_t ws_size,
                              hipStream_t stream) {
    const float* xa   = (const float*)d_in[0];
    const float* efa  = (const float*)d_in[1];
    const int*   ea   = (const int*)d_in[2];
    const float* xb   = (const float*)d_in[3];
    const float* efb  = (const float*)d_in[4];
    const int*   eb   = (const int*)d_in[5];
    const int*   pb   = (const int*)d_in[6];
    const float* W_in   = (const float*)d_in[7];
    const float* b_in   = (const float*)d_in[8];
    const float* W_msg  = (const float*)d_in[9];
    const float* b_msg  = (const float*)d_in[10];
    const float* W_node = (const float*)d_in[11];
    const float* b_node = (const float*)d_in[12];
    const float* W1 = (const float*)d_in[13]; const float* b1 = (const float*)d_in[14];
    const float* W2 = (const float*)d_in[15]; const float* b2 = (const float*)d_in[16];
    const float* W3 = (const float*)d_in[17]; const float* b3 = (const float*)d_in[18];
    const float* W4 = (const float*)d_in[19]; const float* b4 = (const float*)d_in[20];
    const float* W5 = (const float*)d_in[21]; const float* b5 = (const float*)d_in[22];
    const float* W6 = (const float*)d_in[23]; const float* b6 = (const float*)d_in[24];

    int Na = in_sizes[0] / 5;
    int Ea = in_sizes[2] / 2;
    int Nb = in_sizes[3] / 5;
    int Eb = in_sizes[5] / 2;
    int NC = in_sizes[6] / 2;
    int N = Na + Nb;
    int E = Ea + Eb + 2 * NC;
    int off = Ea + Eb;
    int nPart = (N + 1023) / 1024;

    char* p = (char*)d_ws;
    auto alloc = [&](size_t bytes) { char* r = p; p += (bytes + 255) & ~(size_t)255; return r; };
    int*   src    = (int*)alloc((size_t)E * 4);
    int*   dst    = (int*)alloc((size_t)E * 4);
    int*   counts = (int*)alloc((size_t)N * 4);
    int*   offs   = (int*)alloc((size_t)(N + 1) * 4);
    int*   cursor = (int*)alloc((size_t)N * 4);
    int*   parts  = (int*)alloc((size_t)nPart * 4);
    int*   eSrc   = (int*)alloc((size_t)E * 4);
    int*   eOrig  = (int*)alloc((size_t)E * 4);
    float* h0c    = (float*)alloc((size_t)E * 64 * 4);
    float* agg    = (float*)alloc((size_t)N * 64 * 4);
    float* aggW   = (float*)alloc((size_t)N * 64 * 4);
    float* hsave  = (float*)alloc((size_t)2 * NC * 64 * 4);
    float* nodeh  = (float*)alloc((size_t)N * 32 * 4);
    if ((size_t)(p - (char*)d_ws) > ws_size) return;  // insufficient workspace -> visible failure

    hipMemsetAsync(counts, 0, (size_t)N * 4, stream);
    hipMemsetAsync(cursor, 0, (size_t)N * 4, stream);

    build_edges_k<<<(E + TPB - 1) / TPB, TPB, 0, stream>>>(ea, eb, pb, Ea, Eb, NC, Na, src, dst);
    count_k<<<(E + TPB - 1) / TPB, TPB, 0, stream>>>(dst, counts, E);
    scan1_k<<<nPart, TPB, 0, stream>>>(counts, offs, parts, N);
    scan2_k<<<1, 64, 0, stream>>>(parts, nPart);
    scan3_k<<<(N + 1 + TPB - 1) / TPB, TPB, 0, stream>>>(offs, parts, N, E);
    fill_k<<<(E + TPB - 1) / TPB, TPB, 0, stream>>>(src, dst, offs, cursor, eSrc, eOrig, E);
    h0c_k<<<(E * 64 + TPB - 1) / TPB, TPB, 0, stream>>>(xa, xb, efa, efb, eSrc, eOrig,
                                                        Ea, Eb, Na, E, W_in, b_in, h0c);

    int ggrid = (N * 16 + TPB - 1) / TPB;
    int nblk = (N + 63) / 64;
    const float4* h04 = (const float4*)h0c;
    float4* agg4 = (float4*)agg;
    float4* hs4 = (float4*)hsave;

    // agg = segsum(h_1) with h_1 = h0
    gather_k<0><<<ggrid, TPB, 0, stream>>>(h04, eSrc, eOrig, offs, nullptr, agg4, nullptr, N, off);
    // 100 message-passing steps
    for (int t = 1; t <= 100; t++) {
        gemm_k<<<nblk, TPB, 0, stream>>>(agg, W_msg, b_msg, aggW, N);
        if (t < 100)
            gather_k<1><<<ggrid, TPB, 0, stream>>>(h04, eSrc, eOrig, offs, (const float4*)aggW,
                                                   agg4, nullptr, N, off);
        else
            gather_k<2><<<ggrid, TPB, 0, stream>>>(h04, eSrc, eOrig, offs, (const float4*)aggW,
                                                   agg4, hs4, N, off);
    }

    nodeh_k<<<((size_t)N * 32 + TPB - 1) / TPB, TPB, 0, stream>>>(xa, xb, Na, N, agg, W_node, b_node, nodeh);
    mlp2_k<<<(NC + TM2 - 1) / TM2, TPB, 0, stream>>>(nodeh, hsave, pb, NC, Na,
                                                     W1, b1, W2, b2, W3, b3, W4, b4, W5, b5, W6, b6,
                                                     (float*)d_out);
}